// Round 1
// baseline (4245.938 us; speedup 1.0000x reference)
//
#include <hip/hip_runtime.h>
#include <hip/hip_bf16.h>

#define NN   16384
#define IND  512
#define HID  256
#define SAMP 8
#define CAP  64          // max nonzeros per adjacency row (mean ~16.4, P(>64) ~ e^-33)

typedef __bf16 bf16;
typedef __bf16 bf16x4 __attribute__((ext_vector_type(4)));
typedef __bf16 bf16x8 __attribute__((ext_vector_type(8)));
typedef float  f32x4  __attribute__((ext_vector_type(4)));

#define LOG2E_2 2.8853900817779268f   // 2/tau * log2(e) = 2*log2(e)

// ---------------------------------------------------------------- conversions
__global__ void cvt_x(const float* __restrict__ a, bf16* __restrict__ oa,
                      const float* __restrict__ b, bf16* __restrict__ ob) {
  const float* src = blockIdx.y ? b : a;
  bf16* dst = blockIdx.y ? ob : oa;
  int stride = gridDim.x * blockDim.x;
  for (int i = blockIdx.x * blockDim.x + threadIdx.x; i < (NN * IND) / 4; i += stride) {
    float4 v = ((const float4*)src)[i];
    bf16x4 o = {(bf16)v.x, (bf16)v.y, (bf16)v.z, (bf16)v.w};
    *(bf16x4*)(dst + (size_t)i * 4) = o;
  }
}

struct WtArgs {
  const float* src[10];
  bf16* dst[10];
  int K[10];
};

// W [K,256] f32 -> Wt [256,K] bf16 (transposed so GEMM reads K-contiguous rows)
__global__ void cvt_weights(WtArgs a) {
  int w = blockIdx.y;
  int K = a.K[w];
  int total = K * HID;
  const float* s = a.src[w];
  bf16* d = a.dst[w];
  for (int i = blockIdx.x * blockDim.x + threadIdx.x; i < total; i += gridDim.x * blockDim.x) {
    int k = i >> 8, n = i & 255;          // i = k*256 + n
    d[n * K + k] = (bf16)s[i];
  }
}

// ---------------------------------------------------------------- adjacency scan
// one block per row; values are all 1/rowcount so we only record columns+count
__global__ void scan_adj(const float* __restrict__ adj, int* __restrict__ cols,
                         int* __restrict__ cnt) {
  int r = blockIdx.x;
  __shared__ int c;
  if (threadIdx.x == 0) c = 0;
  __syncthreads();
  const float4* row = (const float4*)(adj + (size_t)r * NN);
  int* rc = cols + (size_t)r * CAP;
  for (int i = threadIdx.x; i < NN / 4; i += blockDim.x) {
    float4 v = row[i];
    if (v.x != 0.f || v.y != 0.f || v.z != 0.f || v.w != 0.f) {
      if (v.x != 0.f) { int p = atomicAdd(&c, 1); if (p < CAP) rc[p] = 4 * i; }
      if (v.y != 0.f) { int p = atomicAdd(&c, 1); if (p < CAP) rc[p] = 4 * i + 1; }
      if (v.z != 0.f) { int p = atomicAdd(&c, 1); if (p < CAP) rc[p] = 4 * i + 2; }
      if (v.w != 0.f) { int p = atomicAdd(&c, 1); if (p < CAP) rc[p] = 4 * i + 3; }
    }
  }
  __syncthreads();
  if (threadIdx.x == 0) cnt[r] = (c < CAP) ? c : CAP;
}

// ---------------------------------------------------------------- SpMM
// out[r,:] = (1/max(cnt,1)) * sum_nz X[col,:] + bias ; one wave per row
__global__ void spmm(const int* __restrict__ cols, const int* __restrict__ cnt,
                     const float* __restrict__ X, const float* __restrict__ bias,
                     float* __restrict__ outF, bf16* __restrict__ outB) {
  int wid = threadIdx.x >> 6, lane = threadIdx.x & 63;
  int r = blockIdx.x * 4 + wid;
  int c = cnt[r];
  float val = 1.0f / (float)(c > 0 ? c : 1);
  const int* rc = cols + (size_t)r * CAP;
  float ax = 0.f, ay = 0.f, az = 0.f, aw = 0.f;
  for (int t = 0; t < c; ++t) {
    int col = rc[t];
    float4 v = ((const float4*)(X + (size_t)col * HID))[lane];
    ax += v.x; ay += v.y; az += v.z; aw += v.w;
  }
  float4 b4 = ((const float4*)bias)[lane];
  ax = ax * val + b4.x; ay = ay * val + b4.y; az = az * val + b4.z; aw = aw * val + b4.w;
  if (outF) {   // scalar stores: h3 lands at d_out+3 floats (only 4B-aligned)
    float* o = outF + (size_t)r * HID + lane * 4;
    o[0] = ax; o[1] = ay; o[2] = az; o[3] = aw;
  }
  if (outB) {
    bf16x4 ob = {(bf16)ax, (bf16)ay, (bf16)az, (bf16)aw};
    *(bf16x4*)(outB + (size_t)r * HID + lane * 4) = ob;
  }
}

// ---------------------------------------------------------------- bf16 GEMM (B^T input)
// C[M=16384, N=256] = A[M,K] @ Bt[256,K]^T (+bias) (opt relu) -> f32 and/or bf16
__global__ __launch_bounds__(256) void gemm_bt(
    const bf16* __restrict__ A, const bf16* __restrict__ Bt,
    const float* __restrict__ bias, float* __restrict__ Cf, bf16* __restrict__ Cb,
    int K, int relu) {
  __shared__ bf16 As[128][72];   // +8 pad: row stride 144B breaks power-of-2 conflicts
  __shared__ bf16 Bs[128][72];
  int m0 = blockIdx.x * 128, n0 = blockIdx.y * 128;
  int tid = threadIdx.x, wid = tid >> 6, lane = tid & 63;
  int wm = wid >> 1, wn = wid & 1, q = lane >> 4, li = lane & 15;
  f32x4 acc[4][4] = {};
  for (int k0 = 0; k0 < K; k0 += 64) {
    __syncthreads();
    #pragma unroll
    for (int ch = tid; ch < 1024; ch += 256) {
      int row = ch >> 3, kc = ch & 7;
      *(uint4*)(&As[row][kc * 8]) = *(const uint4*)(A + (size_t)(m0 + row) * K + k0 + kc * 8);
    }
    #pragma unroll
    for (int ch = tid; ch < 1024; ch += 256) {
      int row = ch >> 3, kc = ch & 7;
      *(uint4*)(&Bs[row][kc * 8]) = *(const uint4*)(Bt + (size_t)(n0 + row) * K + k0 + kc * 8);
    }
    __syncthreads();
    #pragma unroll
    for (int kk = 0; kk < 64; kk += 32) {
      bf16x8 af[4], bfr[4];
      #pragma unroll
      for (int im = 0; im < 4; ++im) af[im] = *(const bf16x8*)(&As[wm * 64 + im * 16 + li][kk + q * 8]);
      #pragma unroll
      for (int in = 0; in < 4; ++in) bfr[in] = *(const bf16x8*)(&Bs[wn * 64 + in * 16 + li][kk + q * 8]);
      #pragma unroll
      for (int im = 0; im < 4; ++im)
        #pragma unroll
        for (int in = 0; in < 4; ++in)
          acc[im][in] = __builtin_amdgcn_mfma_f32_16x16x32_bf16(af[im], bfr[in], acc[im][in], 0, 0, 0);
    }
  }
  #pragma unroll
  for (int im = 0; im < 4; ++im) {
    int grow0 = m0 + wm * 64 + im * 16 + q * 4;
    #pragma unroll
    for (int in = 0; in < 4; ++in) {
      int gcol = n0 + wn * 64 + in * 16 + li;
      float bv = bias ? bias[gcol] : 0.f;
      #pragma unroll
      for (int reg = 0; reg < 4; ++reg) {
        float v = acc[im][in][reg] + bv;
        if (relu) v = fmaxf(v, 0.f);
        size_t idx = (size_t)(grow0 + reg) * HID + gcol;
        if (Cf) Cf[idx] = v;
        if (Cb) Cb[idx] = (bf16)v;
      }
    }
  }
}

// ---------------------------------------------------------------- flash semi-loss
// z=0: rowsum exp(2 P·P^T) -> Ra ; z=1: Q·Q^T -> Rb ; z=2: P·Q^T rowsum->Cr colsum->Cc
__global__ __launch_bounds__(256) void flash_sem(
    const bf16* __restrict__ P, const bf16* __restrict__ Q,
    float* __restrict__ Ra, float* __restrict__ Rb,
    float* __restrict__ Cr, float* __restrict__ Cc) {
  __shared__ bf16 As[128][72];
  __shared__ bf16 Bs[128][72];
  const bf16 *X, *Y;
  float* rowacc;
  float* colacc = nullptr;
  if (blockIdx.z == 0)      { X = P; Y = P; rowacc = Ra; }
  else if (blockIdx.z == 1) { X = Q; Y = Q; rowacc = Rb; }
  else                      { X = P; Y = Q; rowacc = Cr; colacc = Cc; }
  // 16x16 tile-group swizzle: 256 consecutive blocks share 32 tiles (2 MiB) -> L2-resident
  int bid = blockIdx.y * 128 + blockIdx.x;
  int grp = bid >> 8, loc = bid & 255;
  int bx = (grp & 7) * 16 + (loc & 15);
  int by = (grp >> 3) * 16 + (loc >> 4);
  int m0 = bx * 128, n0 = by * 128;
  int tid = threadIdx.x, wid = tid >> 6, lane = tid & 63;
  int wm = wid >> 1, wn = wid & 1, q = lane >> 4, li = lane & 15;
  f32x4 acc[4][4] = {};
  for (int k0 = 0; k0 < HID; k0 += 64) {
    __syncthreads();
    #pragma unroll
    for (int ch = tid; ch < 1024; ch += 256) {
      int row = ch >> 3, kc = ch & 7;
      *(uint4*)(&As[row][kc * 8]) = *(const uint4*)(X + (size_t)(m0 + row) * HID + k0 + kc * 8);
    }
    #pragma unroll
    for (int ch = tid; ch < 1024; ch += 256) {
      int row = ch >> 3, kc = ch & 7;
      *(uint4*)(&Bs[row][kc * 8]) = *(const uint4*)(Y + (size_t)(n0 + row) * HID + k0 + kc * 8);
    }
    __syncthreads();
    #pragma unroll
    for (int kk = 0; kk < 64; kk += 32) {
      bf16x8 af[4], bfr[4];
      #pragma unroll
      for (int im = 0; im < 4; ++im) af[im] = *(const bf16x8*)(&As[wm * 64 + im * 16 + li][kk + q * 8]);
      #pragma unroll
      for (int in = 0; in < 4; ++in) bfr[in] = *(const bf16x8*)(&Bs[wn * 64 + in * 16 + li][kk + q * 8]);
      #pragma unroll
      for (int im = 0; im < 4; ++im)
        #pragma unroll
        for (int in = 0; in < 4; ++in)
          acc[im][in] = __builtin_amdgcn_mfma_f32_16x16x32_bf16(af[im], bfr[in], acc[im][in], 0, 0, 0);
    }
  }
  float cs[4] = {0.f, 0.f, 0.f, 0.f};
  #pragma unroll
  for (int im = 0; im < 4; ++im) {
    #pragma unroll
    for (int reg = 0; reg < 4; ++reg) {
      float rs = 0.f;
      #pragma unroll
      for (int in = 0; in < 4; ++in) {
        float e = exp2f(acc[im][in][reg] * LOG2E_2);
        rs += e;
        cs[in] += e;
      }
      rs += __shfl_xor(rs, 1); rs += __shfl_xor(rs, 2);
      rs += __shfl_xor(rs, 4); rs += __shfl_xor(rs, 8);
      if (li == 0) atomicAdd(&rowacc[m0 + wm * 64 + im * 16 + q * 4 + reg], rs);
    }
  }
  if (colacc) {
    #pragma unroll
    for (int in = 0; in < 4; ++in) {
      float v = cs[in];
      v += __shfl_xor(v, 16); v += __shfl_xor(v, 32);
      if (q == 0) atomicAdd(&colacc[n0 + wn * 64 + in * 16 + li], v);
    }
  }
}

// ---------------------------------------------------------------- l2norm (one wave/row)
__global__ void l2norm_k(const float* __restrict__ X, float* __restrict__ outF,
                         bf16* __restrict__ outB) {
  int wid = threadIdx.x >> 6, lane = threadIdx.x & 63;
  int r = blockIdx.x * 4 + wid;
  const float* row = X + (size_t)r * HID + lane * 4;   // scalar loads: X may be d_out+3
  float a0 = row[0], a1 = row[1], a2 = row[2], a3 = row[3];
  float s = a0 * a0 + a1 * a1 + a2 * a2 + a3 * a3;
  #pragma unroll
  for (int off = 1; off < 64; off <<= 1) s += __shfl_xor(s, off);
  float inv = 1.0f / fmaxf(sqrtf(s), 1e-12f);
  a0 *= inv; a1 *= inv; a2 *= inv; a3 *= inv;
  if (outF) {
    float* o = outF + (size_t)r * HID + lane * 4;
    o[0] = a0; o[1] = a1; o[2] = a2; o[3] = a3;
  }
  if (outB) {
    bf16x4 b = {(bf16)a0, (bf16)a1, (bf16)a2, (bf16)a3};
    *(bf16x4*)(outB + (size_t)r * HID + lane * 4) = b;
  }
}

// ---------------------------------------------------------------- contrastive (one wave/node)
__global__ void contrast_k(const float* __restrict__ proj, const float* __restrict__ vn,
                           const float* __restrict__ ue, const int* __restrict__ nbr,
                           const int* __restrict__ neg, float* __restrict__ gsum) {
  int wid = threadIdx.x >> 6, lane = threadIdx.x & 63;
  int n = blockIdx.x * 4 + wid;
  float4 p = ((const float4*)(proj + (size_t)n * HID))[lane];
  float4 v = ((const float4*)(vn + (size_t)n * HID))[lane];
  float du[SAMP], dn[SAMP];
  for (int s = 0; s < SAMP; ++s) {
    int iu = nbr[n * SAMP + s];
    float4 u = ((const float4*)(ue + (size_t)iu * HID))[lane];
    float d = p.x * u.x + p.y * u.y + p.z * u.z + p.w * u.w;
    #pragma unroll
    for (int off = 1; off < 64; off <<= 1) d += __shfl_xor(d, off);
    du[s] = d;
    int iv = neg[n * SAMP + s];
    float4 w = ((const float4*)(vn + (size_t)iv * HID))[lane];
    float d2 = v.x * w.x + v.y * w.y + v.z * w.z + v.w * w.w;
    #pragma unroll
    for (int off = 1; off < 64; off <<= 1) d2 += __shfl_xor(d2, off);
    dn[s] = d2;
  }
  float negsum = 0.f;
  for (int s = 0; s < SAMP; ++s) negsum += expf(2.f * dn[s]);
  float ns = 0.f, ps = 0.f;
  for (int s = 0; s < SAMP; ++s) {
    float pl = 2.f * du[s];
    ns += logf(expf(pl) + negsum);
    ps += pl;
  }
  if (lane == 0) atomicAdd(gsum, ns - ps);   // LAMBDA = 1
}

// ---------------------------------------------------------------- sem finalize (one wave/row)
__global__ void sem_fin(const float* __restrict__ P, const float* __restrict__ Q2,
                        const float* __restrict__ Ra, const float* __restrict__ Rb,
                        const float* __restrict__ Cr, const float* __restrict__ Cc,
                        float* __restrict__ ssum) {
  int wid = threadIdx.x >> 6, lane = threadIdx.x & 63;
  int i = blockIdx.x * 4 + wid;
  float4 a = ((const float4*)(P + (size_t)i * HID))[lane];
  float4 b = ((const float4*)(Q2 + (size_t)i * HID))[lane];
  float d = a.x * b.x + a.y * b.y + a.z * b.z + a.w * b.w;
  #pragma unroll
  for (int off = 1; off < 64; off <<= 1) d += __shfl_xor(d, off);
  float db = expf(2.f * d);
  float e2 = expf(2.f);      // diag(refl) of unit-norm rows
  float l1 = -logf(db / (Ra[i] + Cr[i] - e2));
  float l2 = -logf(db / (Rb[i] + Cc[i] - e2));
  if (lane == 0) atomicAdd(ssum, 0.5f * (l1 + l2));
}

__global__ void final_k(const float* __restrict__ sums, float* __restrict__ out) {
  float gacl = sums[0] / (float)(NN * SAMP);
  float sem = sums[1] / (float)NN;
  out[0] = gacl + 0.6f * sem;
  out[1] = gacl;
  out[2] = sem;
}

// ---------------------------------------------------------------- launch
extern "C" void kernel_launch(void* const* d_in, const int* in_sizes, int n_in,
                              void* d_out, int out_size, void* d_ws, size_t ws_size,
                              hipStream_t stream) {
  (void)in_sizes; (void)n_in; (void)out_size; (void)ws_size;
  const float* adj1 = (const float*)d_in[0];
  const float* adj2 = (const float*)d_in[1];
  const float* x1 = (const float*)d_in[2];
  const float* x2 = (const float*)d_in[3];
  const int* nbr = (const int*)d_in[4];
  const int* neg = (const int*)d_in[5];
  const float* W1 = (const float*)d_in[6];
  const float* b1 = (const float*)d_in[7];
  const float* W2 = (const float*)d_in[8];
  const float* b2 = (const float*)d_in[9];
  const float* tW1 = (const float*)d_in[10];
  const float* tb1 = (const float*)d_in[11];
  const float* tW2 = (const float*)d_in[12];
  const float* tb2 = (const float*)d_in[13];
  const float* pB[3] = {(const float*)d_in[15], (const float*)d_in[17], (const float*)d_in[19]};
  const float* sB[3] = {(const float*)d_in[21], (const float*)d_in[23], (const float*)d_in[25]};

  char* w = (char*)d_ws;
  auto alloc = [&](size_t bytes) -> char* {
    char* p = w;
    w += (bytes + 255) & ~(size_t)255;
    return p;
  };
  // accumulators first (one memset covers them)
  float* Ra = (float*)alloc((size_t)NN * 4);
  float* Rb = (float*)alloc((size_t)NN * 4);
  float* Cr = (float*)alloc((size_t)NN * 4);
  float* Cc = (float*)alloc((size_t)NN * 4);
  float* sums = (float*)alloc(256);             // [0]=gacl_sum, [1]=sem_sum
  size_t accBytes = (size_t)(w - (char*)d_ws);

  int* c1cols = (int*)alloc((size_t)NN * CAP * 4);
  int* c1cnt = (int*)alloc((size_t)NN * 4);
  int* c2cols = (int*)alloc((size_t)NN * CAP * 4);
  int* c2cnt = (int*)alloc((size_t)NN * 4);
  bf16* x1b = (bf16*)alloc((size_t)NN * IND * 2);
  bf16* x2b = (bf16*)alloc((size_t)NN * IND * 2);
  bf16* W1t = (bf16*)alloc((size_t)IND * HID * 2);
  bf16* tW1t = (bf16*)alloc((size_t)IND * HID * 2);
  bf16* W2t = (bf16*)alloc((size_t)HID * HID * 2);
  bf16* tW2t = (bf16*)alloc((size_t)HID * HID * 2);
  bf16* pWt[3], *sWt[3];
  for (int i = 0; i < 3; ++i) pWt[i] = (bf16*)alloc((size_t)HID * HID * 2);
  for (int i = 0; i < 3; ++i) sWt[i] = (bf16*)alloc((size_t)HID * HID * 2);
  const size_t FB = (size_t)NN * HID * 4;       // 16 MiB f32 buffers
  float* xw1 = (float*)alloc(FB);
  float* xw2 = (float*)alloc(FB);
  float* xt1 = (float*)alloc(FB);
  float* u_pre = (float*)alloc(FB);
  float* mlp_out = (float*)alloc(FB);
  float* projected = (float*)alloc(FB);
  float* h1p = (float*)alloc(FB);
  float* h2p = (float*)alloc(FB);
  float* v_norm = (float*)alloc(FB);
  float* gw = xw2;       // reuse: xw2 dead after spmm(h2)
  float* utw = xt1;      // reuse: xt1 dead after spmm(ut)
  float* u_emd = xw1;    // reuse: xw1 dead after spmm(g)
  const size_t BB = (size_t)NN * HID * 2;       // 8 MiB bf16 buffers
  bf16* h1b = (bf16*)alloc(BB);
  bf16* h2b = (bf16*)alloc(BB);
  bf16* gb = (bf16*)alloc(BB);
  bf16* h3b = (bf16*)alloc(BB);
  bf16* utb = (bf16*)alloc(BB);
  bf16* mA = (bf16*)alloc(BB);
  bf16* mB = (bf16*)alloc(BB);
  bf16* Pb = gb;         // reuse: gb dead after gemm(gw)
  bf16* Qb = utb;        // reuse: utb dead after gemm(utw)

  hipMemsetAsync(d_ws, 0, accBytes, stream);

  WtArgs wa;
  const float* wsrc[10] = {W1, tW1, W2, tW2,
                           (const float*)d_in[14], (const float*)d_in[16], (const float*)d_in[18],
                           (const float*)d_in[20], (const float*)d_in[22], (const float*)d_in[24]};
  bf16* wdst[10] = {W1t, tW1t, W2t, tW2t, pWt[0], pWt[1], pWt[2], sWt[0], sWt[1], sWt[2]};
  int wk[10] = {IND, IND, HID, HID, HID, HID, HID, HID, HID, HID};
  for (int i = 0; i < 10; ++i) { wa.src[i] = wsrc[i]; wa.dst[i] = wdst[i]; wa.K[i] = wk[i]; }
  cvt_weights<<<dim3(512, 10), 256, 0, stream>>>(wa);
  cvt_x<<<dim3(2048, 2), 256, 0, stream>>>(x1, x1b, x2, x2b);
  scan_adj<<<NN, 256, 0, stream>>>(adj1, c1cols, c1cnt);
  scan_adj<<<NN, 256, 0, stream>>>(adj2, c2cols, c2cnt);

  dim3 gg(NN / 128, HID / 128);
  gemm_bt<<<gg, 256, 0, stream>>>(x1b, W1t, nullptr, xw1, nullptr, IND, 0);
  gemm_bt<<<gg, 256, 0, stream>>>(x2b, W1t, nullptr, xw2, nullptr, IND, 0);
  gemm_bt<<<gg, 256, 0, stream>>>(x1b, tW1t, nullptr, xt1, nullptr, IND, 0);

  spmm<<<NN / 4, 256, 0, stream>>>(c1cols, c1cnt, xw1, b1, nullptr, h1b);
  spmm<<<NN / 4, 256, 0, stream>>>(c1cols, c1cnt, xw2, b1, nullptr, h2b);
  spmm<<<NN / 4, 256, 0, stream>>>(c2cols, c2cnt, xw1, b1, nullptr, gb);
  spmm<<<NN / 4, 256, 0, stream>>>(c2cols, c2cnt, xt1, tb1, nullptr, utb);

  gemm_bt<<<gg, 256, 0, stream>>>(gb, W2t, nullptr, gw, nullptr, HID, 0);
  float* h3out = ((float*)d_out) + 3;
  spmm<<<NN / 4, 256, 0, stream>>>(c2cols, c2cnt, gw, b2, h3out, h3b);

  gemm_bt<<<gg, 256, 0, stream>>>(utb, tW2t, nullptr, utw, nullptr, HID, 0);
  spmm<<<NN / 4, 256, 0, stream>>>(c2cols, c2cnt, utw, tb2, u_pre, nullptr);
  l2norm_k<<<NN / 4, 256, 0, stream>>>(u_pre, u_emd, nullptr);
  l2norm_k<<<NN / 4, 256, 0, stream>>>(h3out, v_norm, nullptr);

  // projection MLP on h3
  gemm_bt<<<gg, 256, 0, stream>>>(h3b, pWt[0], pB[0], nullptr, mA, HID, 1);
  gemm_bt<<<gg, 256, 0, stream>>>(mA, pWt[1], pB[1], nullptr, mB, HID, 1);
  gemm_bt<<<gg, 256, 0, stream>>>(mB, pWt[2], pB[2], mlp_out, nullptr, HID, 0);
  l2norm_k<<<NN / 4, 256, 0, stream>>>(mlp_out, projected, nullptr);
  // sem MLP on h1
  gemm_bt<<<gg, 256, 0, stream>>>(h1b, sWt[0], sB[0], nullptr, mA, HID, 1);
  gemm_bt<<<gg, 256, 0, stream>>>(mA, sWt[1], sB[1], nullptr, mB, HID, 1);
  gemm_bt<<<gg, 256, 0, stream>>>(mB, sWt[2], sB[2], mlp_out, nullptr, HID, 0);
  l2norm_k<<<NN / 4, 256, 0, stream>>>(mlp_out, h1p, Pb);
  // sem MLP on h2
  gemm_bt<<<gg, 256, 0, stream>>>(h2b, sWt[0], sB[0], nullptr, mA, HID, 1);
  gemm_bt<<<gg, 256, 0, stream>>>(mA, sWt[1], sB[1], nullptr, mB, HID, 1);
  gemm_bt<<<gg, 256, 0, stream>>>(mB, sWt[2], sB[2], mlp_out, nullptr, HID, 0);
  l2norm_k<<<NN / 4, 256, 0, stream>>>(mlp_out, h2p, Qb);

  flash_sem<<<dim3(128, 128, 3), 256, 0, stream>>>(Pb, Qb, Ra, Rb, Cr, Cc);
  contrast_k<<<NN / 4, 256, 0, stream>>>(projected, v_norm, u_emd, nbr, neg, &sums[0]);
  sem_fin<<<NN / 4, 256, 0, stream>>>(h1p, h2p, Ra, Rb, Cr, Cc, &sums[1]);
  final_k<<<1, 1, 0, stream>>>(sums, (float*)d_out);
}

// Round 2
// 3539.649 us; speedup vs baseline: 1.1995x; 1.1995x over previous
//
#include <hip/hip_runtime.h>
#include <hip/hip_bf16.h>

#define NN   16384
#define IND  512
#define HID  256
#define SAMP 8
#define CAP  64          // max nonzeros per adjacency row (mean ~16.4, P(>64) ~ e^-33)

typedef __bf16 bf16;
typedef __bf16 bf16x4 __attribute__((ext_vector_type(4)));
typedef __bf16 bf16x8 __attribute__((ext_vector_type(8)));
typedef float  f32x4  __attribute__((ext_vector_type(4)));

#define LOG2E_2 2.8853900817779268f   // 2/tau * log2(e) = 2*log2(e)

// async global->LDS, 16B per lane; LDS dest = wave-uniform base + lane*16
#define GLOAD_LDS16(gptr, lptr) \
  __builtin_amdgcn_global_load_lds((const __attribute__((address_space(1))) void*)(gptr), \
                                   (__attribute__((address_space(3))) void*)(lptr), 16, 0, 0)

// ---------------------------------------------------------------- conversions
__global__ void cvt_x(const float* __restrict__ a, bf16* __restrict__ oa,
                      const float* __restrict__ b, bf16* __restrict__ ob) {
  const float* src = blockIdx.y ? b : a;
  bf16* dst = blockIdx.y ? ob : oa;
  int stride = gridDim.x * blockDim.x;
  for (int i = blockIdx.x * blockDim.x + threadIdx.x; i < (NN * IND) / 4; i += stride) {
    float4 v = ((const float4*)src)[i];
    bf16x4 o = {(bf16)v.x, (bf16)v.y, (bf16)v.z, (bf16)v.w};
    *(bf16x4*)(dst + (size_t)i * 4) = o;
  }
}

struct WtArgs {
  const float* src[10];
  bf16* dst[10];
  int K[10];
};

// W [K,256] f32 -> Wt [256,K] bf16 (transposed so GEMM reads K-contiguous rows)
__global__ void cvt_weights(WtArgs a) {
  int w = blockIdx.y;
  int K = a.K[w];
  int total = K * HID;
  const float* s = a.src[w];
  bf16* d = a.dst[w];
  for (int i = blockIdx.x * blockDim.x + threadIdx.x; i < total; i += gridDim.x * blockDim.x) {
    int k = i >> 8, n = i & 255;          // i = k*256 + n
    d[n * K + k] = (bf16)s[i];
  }
}

// ---------------------------------------------------------------- adjacency scan (batched)
__global__ void scan_adj(const float* __restrict__ adjA, const float* __restrict__ adjB,
                         int* __restrict__ colsA, int* __restrict__ cntA,
                         int* __restrict__ colsB, int* __restrict__ cntB) {
  const float* adj = blockIdx.y ? adjB : adjA;
  int* cols = blockIdx.y ? colsB : colsA;
  int* cnt = blockIdx.y ? cntB : cntA;
  int r = blockIdx.x;
  __shared__ int c;
  if (threadIdx.x == 0) c = 0;
  __syncthreads();
  const float4* row = (const float4*)(adj + (size_t)r * NN);
  int* rc = cols + (size_t)r * CAP;
  for (int i = threadIdx.x; i < NN / 4; i += blockDim.x) {
    float4 v = row[i];
    if (v.x != 0.f || v.y != 0.f || v.z != 0.f || v.w != 0.f) {
      if (v.x != 0.f) { int p = atomicAdd(&c, 1); if (p < CAP) rc[p] = 4 * i; }
      if (v.y != 0.f) { int p = atomicAdd(&c, 1); if (p < CAP) rc[p] = 4 * i + 1; }
      if (v.z != 0.f) { int p = atomicAdd(&c, 1); if (p < CAP) rc[p] = 4 * i + 2; }
      if (v.w != 0.f) { int p = atomicAdd(&c, 1); if (p < CAP) rc[p] = 4 * i + 3; }
    }
  }
  __syncthreads();
  if (threadIdx.x == 0) cnt[r] = (c < CAP) ? c : CAP;
}

// ---------------------------------------------------------------- SpMM (batched, opt fused l2norm)
struct SpmmB {
  const int* cols[4]; const int* cnt[4]; const float* X[4]; const float* bias[4];
  float* outF[4];   // raw f32 (scalar stores; may be 4B-aligned only)
  bf16* outB[4];    // raw bf16
  float* outNF[4];  // l2-normalized f32 (16B-aligned)
};
__global__ void spmm_b(SpmmB s) {
  int j = blockIdx.y;
  int wid = threadIdx.x >> 6, lane = threadIdx.x & 63;
  int r = blockIdx.x * 4 + wid;
  int c = s.cnt[j][r];
  float val = 1.0f / (float)(c > 0 ? c : 1);
  const int* rc = s.cols[j] + (size_t)r * CAP;
  const float* X = s.X[j];
  float ax = 0.f, ay = 0.f, az = 0.f, aw = 0.f;
  for (int t = 0; t < c; ++t) {
    int col = rc[t];
    float4 v = ((const float4*)(X + (size_t)col * HID))[lane];
    ax += v.x; ay += v.y; az += v.z; aw += v.w;
  }
  float4 b4 = ((const float4*)s.bias[j])[lane];
  ax = ax * val + b4.x; ay = ay * val + b4.y; az = az * val + b4.z; aw = aw * val + b4.w;
  if (s.outF[j]) {
    float* o = s.outF[j] + (size_t)r * HID + lane * 4;
    o[0] = ax; o[1] = ay; o[2] = az; o[3] = aw;
  }
  if (s.outB[j]) {
    bf16x4 ob = {(bf16)ax, (bf16)ay, (bf16)az, (bf16)aw};
    *(bf16x4*)(s.outB[j] + (size_t)r * HID + lane * 4) = ob;
  }
  if (s.outNF[j]) {
    float ss = ax * ax + ay * ay + az * az + aw * aw;
    #pragma unroll
    for (int off = 1; off < 64; off <<= 1) ss += __shfl_xor(ss, off);
    float inv = 1.0f / fmaxf(sqrtf(ss), 1e-12f);
    float4 o = {ax * inv, ay * inv, az * inv, aw * inv};
    ((float4*)(s.outNF[j] + (size_t)r * HID))[lane] = o;
  }
}

// ---------------------------------------------------------------- bf16 GEMM (batched, async staging)
// C[M=16384, N=256] = A[M,K] @ Bt[256,K]^T (+bias) (opt relu) -> f32 and/or bf16
struct GemmB {
  const bf16* A[3]; const bf16* Bt[3]; const float* bias[3];
  float* Cf[3]; bf16* Cb[3];
};
__global__ __launch_bounds__(256) void gemm_b(GemmB g, int K, int relu) {
  __shared__ bf16 As[128][64];   // unpadded: global_load_lds needs contiguous lane order
  __shared__ bf16 Bs[128][64];
  int j = blockIdx.z;
  const bf16* A = g.A[j];
  const bf16* Bt = g.Bt[j];
  int m0 = blockIdx.x * 128, n0 = blockIdx.y * 128;
  int tid = threadIdx.x, wid = tid >> 6, lane = tid & 63;
  int wm = wid >> 1, wn = wid & 1, q = lane >> 4, li = lane & 15;
  int r8 = lane >> 3, cc8 = lane & 7;    // 8 rows x 8 chunks per wave-instruction
  f32x4 acc[4][4] = {};
  for (int k0 = 0; k0 < K; k0 += 64) {
    if (k0) __syncthreads();
    const bf16* gA = A + (size_t)(m0 + wid * 32 + r8) * K + k0 + cc8 * 8;
    const bf16* gB = Bt + (size_t)(n0 + wid * 32 + r8) * K + k0 + cc8 * 8;
    #pragma unroll
    for (int jj = 0; jj < 4; ++jj) {
      GLOAD_LDS16(gA + (size_t)jj * 8 * K, &As[wid * 32 + jj * 8][0]);
      GLOAD_LDS16(gB + (size_t)jj * 8 * K, &Bs[wid * 32 + jj * 8][0]);
    }
    __syncthreads();
    #pragma unroll
    for (int kk = 0; kk < 64; kk += 32) {
      bf16x8 af[4], bfr[4];
      #pragma unroll
      for (int im = 0; im < 4; ++im) af[im] = *(const bf16x8*)(&As[wm * 64 + im * 16 + li][kk + q * 8]);
      #pragma unroll
      for (int in = 0; in < 4; ++in) bfr[in] = *(const bf16x8*)(&Bs[wn * 64 + in * 16 + li][kk + q * 8]);
      #pragma unroll
      for (int im = 0; im < 4; ++im)
        #pragma unroll
        for (int in = 0; in < 4; ++in)
          acc[im][in] = __builtin_amdgcn_mfma_f32_16x16x32_bf16(af[im], bfr[in], acc[im][in], 0, 0, 0);
    }
  }
  float* Cf = g.Cf[j];
  bf16* Cb = g.Cb[j];
  const float* bias = g.bias[j];
  #pragma unroll
  for (int im = 0; im < 4; ++im) {
    int grow0 = m0 + wm * 64 + im * 16 + q * 4;
    #pragma unroll
    for (int in = 0; in < 4; ++in) {
      int gcol = n0 + wn * 64 + in * 16 + li;
      float bv = bias ? bias[gcol] : 0.f;
      #pragma unroll
      for (int reg = 0; reg < 4; ++reg) {
        float v = acc[im][in][reg] + bv;
        if (relu) v = fmaxf(v, 0.f);
        size_t idx = (size_t)(grow0 + reg) * HID + gcol;
        if (Cf) Cf[idx] = v;
        if (Cb) Cb[idx] = (bf16)v;
      }
    }
  }
}

// ---------------------------------------------------------------- flash semi-loss v2
// z=0: exp(2 P·P^T) rowsums -> Ra (upper triangle only; off-diag tiles add colsum to Ra too)
// z=1: same for Q -> Rb ; z=2: P·Q^T full, rowsum->Cr colsum->Cc
__global__ __launch_bounds__(256) void flash_sem2(
    const bf16* __restrict__ P, const bf16* __restrict__ Q,
    float* __restrict__ Ra, float* __restrict__ Rb,
    float* __restrict__ Cr, float* __restrict__ Cc) {
  __shared__ bf16 As[128][64];
  __shared__ bf16 Bs[128][64];
  int z = blockIdx.z;
  // 16x16 tile-group swizzle for L2 locality
  int bid = blockIdx.y * 128 + blockIdx.x;
  int grp = bid >> 8, loc = bid & 255;
  int bx = (grp & 7) * 16 + (loc & 15);
  int by = (grp >> 3) * 16 + (loc >> 4);
  if (z < 2 && by < bx) return;     // symmetric: upper triangle only
  const bf16* X = (z == 1) ? Q : P;
  const bf16* Y = (z == 0) ? P : Q;
  float* rowacc = (z == 0) ? Ra : (z == 1) ? Rb : Cr;
  float* colacc = (z == 2) ? Cc : rowacc;   // symmetric off-diag: colsum -> same acc
  bool docol = (z == 2) || (bx != by);
  int m0 = bx * 128, n0 = by * 128;
  int tid = threadIdx.x, wid = tid >> 6, lane = tid & 63;
  int wm = wid >> 1, wn = wid & 1, q = lane >> 4, li = lane & 15;
  int r8 = lane >> 3, cc8 = lane & 7;
  f32x4 acc[4][4] = {};
  for (int k0 = 0; k0 < HID; k0 += 64) {
    if (k0) __syncthreads();
    const bf16* gA = X + (size_t)(m0 + wid * 32 + r8) * HID + k0 + cc8 * 8;
    const bf16* gB = Y + (size_t)(n0 + wid * 32 + r8) * HID + k0 + cc8 * 8;
    #pragma unroll
    for (int jj = 0; jj < 4; ++jj) {
      GLOAD_LDS16(gA + (size_t)jj * 8 * HID, &As[wid * 32 + jj * 8][0]);
      GLOAD_LDS16(gB + (size_t)jj * 8 * HID, &Bs[wid * 32 + jj * 8][0]);
    }
    __syncthreads();
    #pragma unroll
    for (int kk = 0; kk < 64; kk += 32) {
      bf16x8 af[4], bfr[4];
      #pragma unroll
      for (int im = 0; im < 4; ++im) af[im] = *(const bf16x8*)(&As[wm * 64 + im * 16 + li][kk + q * 8]);
      #pragma unroll
      for (int in = 0; in < 4; ++in) bfr[in] = *(const bf16x8*)(&Bs[wn * 64 + in * 16 + li][kk + q * 8]);
      #pragma unroll
      for (int im = 0; im < 4; ++im)
        #pragma unroll
        for (int in = 0; in < 4; ++in)
          acc[im][in] = __builtin_amdgcn_mfma_f32_16x16x32_bf16(af[im], bfr[in], acc[im][in], 0, 0, 0);
    }
  }
  float cs[4] = {0.f, 0.f, 0.f, 0.f};
  #pragma unroll
  for (int im = 0; im < 4; ++im) {
    #pragma unroll
    for (int reg = 0; reg < 4; ++reg) {
      float rs = 0.f;
      #pragma unroll
      for (int in = 0; in < 4; ++in) {
        float e = exp2f(acc[im][in][reg] * LOG2E_2);
        rs += e;
        cs[in] += e;
      }
      rs += __shfl_xor(rs, 1); rs += __shfl_xor(rs, 2);
      rs += __shfl_xor(rs, 4); rs += __shfl_xor(rs, 8);
      if (li == 0) atomicAdd(&rowacc[m0 + wm * 64 + im * 16 + q * 4 + reg], rs);
    }
  }
  if (docol) {
    #pragma unroll
    for (int in = 0; in < 4; ++in) {
      float v = cs[in];
      v += __shfl_xor(v, 16); v += __shfl_xor(v, 32);
      if (q == 0) atomicAdd(&colacc[n0 + wn * 64 + in * 16 + li], v);
    }
  }
}

// ---------------------------------------------------------------- l2norm (batched, one wave/row)
struct NormB { const float* X[3]; float* outF[3]; bf16* outB[3]; };
__global__ void l2norm_b(NormB n) {
  int j = blockIdx.y;
  int wid = threadIdx.x >> 6, lane = threadIdx.x & 63;
  int r = blockIdx.x * 4 + wid;
  float4 a = ((const float4*)(n.X[j] + (size_t)r * HID))[lane];
  float s = a.x * a.x + a.y * a.y + a.z * a.z + a.w * a.w;
  #pragma unroll
  for (int off = 1; off < 64; off <<= 1) s += __shfl_xor(s, off);
  float inv = 1.0f / fmaxf(sqrtf(s), 1e-12f);
  a.x *= inv; a.y *= inv; a.z *= inv; a.w *= inv;
  if (n.outF[j]) ((float4*)(n.outF[j] + (size_t)r * HID))[lane] = a;
  if (n.outB[j]) {
    bf16x4 b = {(bf16)a.x, (bf16)a.y, (bf16)a.z, (bf16)a.w};
    *(bf16x4*)(n.outB[j] + (size_t)r * HID + lane * 4) = b;
  }
}

// ---------------------------------------------------------------- contrastive (one wave/node)
__global__ void contrast_k(const float* __restrict__ proj, const float* __restrict__ vn,
                           const float* __restrict__ ue, const int* __restrict__ nbr,
                           const int* __restrict__ neg, float* __restrict__ gsum) {
  int wid = threadIdx.x >> 6, lane = threadIdx.x & 63;
  int n = blockIdx.x * 4 + wid;
  float4 p = ((const float4*)(proj + (size_t)n * HID))[lane];
  float4 v = ((const float4*)(vn + (size_t)n * HID))[lane];
  float du[SAMP], dn[SAMP];
  for (int s = 0; s < SAMP; ++s) {
    int iu = nbr[n * SAMP + s];
    float4 u = ((const float4*)(ue + (size_t)iu * HID))[lane];
    float d = p.x * u.x + p.y * u.y + p.z * u.z + p.w * u.w;
    #pragma unroll
    for (int off = 1; off < 64; off <<= 1) d += __shfl_xor(d, off);
    du[s] = d;
    int iv = neg[n * SAMP + s];
    float4 w = ((const float4*)(vn + (size_t)iv * HID))[lane];
    float d2 = v.x * w.x + v.y * w.y + v.z * w.z + v.w * w.w;
    #pragma unroll
    for (int off = 1; off < 64; off <<= 1) d2 += __shfl_xor(d2, off);
    dn[s] = d2;
  }
  float negsum = 0.f;
  for (int s = 0; s < SAMP; ++s) negsum += expf(2.f * dn[s]);
  float ns = 0.f, ps = 0.f;
  for (int s = 0; s < SAMP; ++s) {
    float pl = 2.f * du[s];
    ns += logf(expf(pl) + negsum);
    ps += pl;
  }
  if (lane == 0) atomicAdd(gsum, ns - ps);   // LAMBDA = 1
}

// ---------------------------------------------------------------- sem finalize (one wave/row)
__global__ void sem_fin(const float* __restrict__ P, const float* __restrict__ Q2,
                        const float* __restrict__ Ra, const float* __restrict__ Rb,
                        const float* __restrict__ Cr, const float* __restrict__ Cc,
                        float* __restrict__ ssum) {
  int wid = threadIdx.x >> 6, lane = threadIdx.x & 63;
  int i = blockIdx.x * 4 + wid;
  float4 a = ((const float4*)(P + (size_t)i * HID))[lane];
  float4 b = ((const float4*)(Q2 + (size_t)i * HID))[lane];
  float d = a.x * b.x + a.y * b.y + a.z * b.z + a.w * b.w;
  #pragma unroll
  for (int off = 1; off < 64; off <<= 1) d += __shfl_xor(d, off);
  float db = expf(2.f * d);
  float e2 = expf(2.f);      // diag(refl) of unit-norm rows
  float l1 = -logf(db / (Ra[i] + Cr[i] - e2));
  float l2 = -logf(db / (Rb[i] + Cc[i] - e2));
  if (lane == 0) atomicAdd(ssum, 0.5f * (l1 + l2));
}

__global__ void final_k(const float* __restrict__ sums, float* __restrict__ out) {
  float gacl = sums[0] / (float)(NN * SAMP);
  float sem = sums[1] / (float)NN;
  out[0] = gacl + 0.6f * sem;
  out[1] = gacl;
  out[2] = sem;
}

// ---------------------------------------------------------------- launch
extern "C" void kernel_launch(void* const* d_in, const int* in_sizes, int n_in,
                              void* d_out, int out_size, void* d_ws, size_t ws_size,
                              hipStream_t stream) {
  (void)in_sizes; (void)n_in; (void)out_size; (void)ws_size;
  const float* adj1 = (const float*)d_in[0];
  const float* adj2 = (const float*)d_in[1];
  const float* x1 = (const float*)d_in[2];
  const float* x2 = (const float*)d_in[3];
  const int* nbr = (const int*)d_in[4];
  const int* neg = (const int*)d_in[5];
  const float* W1 = (const float*)d_in[6];
  const float* b1 = (const float*)d_in[7];
  const float* W2 = (const float*)d_in[8];
  const float* b2 = (const float*)d_in[9];
  const float* tW1 = (const float*)d_in[10];
  const float* tb1 = (const float*)d_in[11];
  const float* tW2 = (const float*)d_in[12];
  const float* tb2 = (const float*)d_in[13];
  const float* pB[3] = {(const float*)d_in[15], (const float*)d_in[17], (const float*)d_in[19]};
  const float* sB[3] = {(const float*)d_in[21], (const float*)d_in[23], (const float*)d_in[25]};

  char* w = (char*)d_ws;
  auto alloc = [&](size_t bytes) -> char* {
    char* p = w;
    w += (bytes + 255) & ~(size_t)255;
    return p;
  };
  // accumulators first (one memset covers them)
  float* Ra = (float*)alloc((size_t)NN * 4);
  float* Rb = (float*)alloc((size_t)NN * 4);
  float* Cr = (float*)alloc((size_t)NN * 4);
  float* Cc = (float*)alloc((size_t)NN * 4);
  float* sums = (float*)alloc(256);             // [0]=gacl_sum, [1]=sem_sum
  size_t accBytes = (size_t)(w - (char*)d_ws);

  int* c1cols = (int*)alloc((size_t)NN * CAP * 4);
  int* c1cnt = (int*)alloc((size_t)NN * 4);
  int* c2cols = (int*)alloc((size_t)NN * CAP * 4);
  int* c2cnt = (int*)alloc((size_t)NN * 4);
  bf16* x1b = (bf16*)alloc((size_t)NN * IND * 2);
  bf16* x2b = (bf16*)alloc((size_t)NN * IND * 2);
  bf16* W1t = (bf16*)alloc((size_t)IND * HID * 2);
  bf16* tW1t = (bf16*)alloc((size_t)IND * HID * 2);
  bf16* W2t = (bf16*)alloc((size_t)HID * HID * 2);
  bf16* tW2t = (bf16*)alloc((size_t)HID * HID * 2);
  bf16* pWt[3], *sWt[3];
  for (int i = 0; i < 3; ++i) pWt[i] = (bf16*)alloc((size_t)HID * HID * 2);
  for (int i = 0; i < 3; ++i) sWt[i] = (bf16*)alloc((size_t)HID * HID * 2);
  const size_t FB = (size_t)NN * HID * 4;       // 16 MiB f32 buffers
  float* xw1 = (float*)alloc(FB);
  float* xw2 = (float*)alloc(FB);
  float* xt1 = (float*)alloc(FB);
  float* mlp_out = (float*)alloc(FB);
  float* projected = (float*)alloc(FB);
  float* h1p = (float*)alloc(FB);
  float* h2p = (float*)alloc(FB);
  float* v_norm = (float*)alloc(FB);
  float* gw = xw2;       // reuse: xw2 dead after spmm(h2)
  float* utw = xt1;      // reuse: xt1 dead after spmm(ut)
  float* u_emd = xw1;    // reuse: xw1 dead after spmm(g)
  const size_t BB = (size_t)NN * HID * 2;       // 8 MiB bf16 buffers
  bf16* h1b = (bf16*)alloc(BB);
  bf16* h2b = (bf16*)alloc(BB);
  bf16* gb = (bf16*)alloc(BB);
  bf16* h3b = (bf16*)alloc(BB);
  bf16* utb = (bf16*)alloc(BB);
  bf16* mA = (bf16*)alloc(BB);
  bf16* mB = (bf16*)alloc(BB);
  // overlays (regions dead by the time they're reused):
  bf16* mB1 = x1b;                       // x1b dead after layer-1 GEMMs
  bf16* mB2 = x1b + (size_t)NN * HID;    // second half of x1b
  bf16* Pb = gb;                         // gb dead after MLP layer 2
  bf16* Qb = utb;

  hipMemsetAsync(d_ws, 0, accBytes, stream);

  WtArgs wa;
  const float* wsrc[10] = {W1, tW1, W2, tW2,
                           (const float*)d_in[14], (const float*)d_in[16], (const float*)d_in[18],
                           (const float*)d_in[20], (const float*)d_in[22], (const float*)d_in[24]};
  bf16* wdst[10] = {W1t, tW1t, W2t, tW2t, pWt[0], pWt[1], pWt[2], sWt[0], sWt[1], sWt[2]};
  int wk[10] = {IND, IND, HID, HID, HID, HID, HID, HID, HID, HID};
  for (int i = 0; i < 10; ++i) { wa.src[i] = wsrc[i]; wa.dst[i] = wdst[i]; wa.K[i] = wk[i]; }
  cvt_weights<<<dim3(512, 10), 256, 0, stream>>>(wa);
  cvt_x<<<dim3(2048, 2), 256, 0, stream>>>(x1, x1b, x2, x2b);
  scan_adj<<<dim3(NN, 2), 256, 0, stream>>>(adj1, adj2, c1cols, c1cnt, c2cols, c2cnt);

  // xw1 = x1@W1, xw2 = x2@W1, xt1 = x1@tW1  (K=512, batched)
  {
    GemmB g = {};
    g.A[0] = x1b; g.Bt[0] = W1t; g.Cf[0] = xw1;
    g.A[1] = x2b; g.Bt[1] = W1t; g.Cf[1] = xw2;
    g.A[2] = x1b; g.Bt[2] = tW1t; g.Cf[2] = xt1;
    gemm_b<<<dim3(128, 2, 3), 256, 0, stream>>>(g, IND, 0);
  }
  // h1 = A1@xw1+b1, h2 = A1@xw2+b1, g = A2@xw1+b1, ut = A2@xt1+tb1
  {
    SpmmB s = {};
    s.cols[0] = c1cols; s.cnt[0] = c1cnt; s.X[0] = xw1; s.bias[0] = b1; s.outB[0] = h1b;
    s.cols[1] = c1cols; s.cnt[1] = c1cnt; s.X[1] = xw2; s.bias[1] = b1; s.outB[1] = h2b;
    s.cols[2] = c2cols; s.cnt[2] = c2cnt; s.X[2] = xw1; s.bias[2] = b1; s.outB[2] = gb;
    s.cols[3] = c2cols; s.cnt[3] = c2cnt; s.X[3] = xt1; s.bias[3] = tb1; s.outB[3] = utb;
    spmm_b<<<dim3(NN / 4, 4), 256, 0, stream>>>(s);
  }
  // gw = g@W2, utw = ut@tW2 (K=256, batched)
  {
    GemmB g = {};
    g.A[0] = gb; g.Bt[0] = W2t; g.Cf[0] = gw;
    g.A[1] = utb; g.Bt[1] = tW2t; g.Cf[1] = utw;
    gemm_b<<<dim3(128, 2, 2), 256, 0, stream>>>(g, HID, 0);
  }
  // h3 = A2@gw+b2 (-> d_out+3, h3b, v_norm) ; u_emd = l2norm(A2@utw+tb2)
  float* h3out = ((float*)d_out) + 3;
  {
    SpmmB s = {};
    s.cols[0] = c2cols; s.cnt[0] = c2cnt; s.X[0] = gw; s.bias[0] = b2;
    s.outF[0] = h3out; s.outB[0] = h3b; s.outNF[0] = v_norm;
    s.cols[1] = c2cols; s.cnt[1] = c2cnt; s.X[1] = utw; s.bias[1] = tb2;
    s.outNF[1] = u_emd;
    spmm_b<<<dim3(NN / 4, 2), 256, 0, stream>>>(s);
  }
  // MLP layer 1 (relu): proj(h3b), sem(h1b), sem(h2b)
  {
    GemmB g = {};
    g.A[0] = h3b; g.Bt[0] = pWt[0]; g.bias[0] = pB[0]; g.Cb[0] = mA;
    g.A[1] = h1b; g.Bt[1] = sWt[0]; g.bias[1] = sB[0]; g.Cb[1] = gb;
    g.A[2] = h2b; g.Bt[2] = sWt[0]; g.bias[2] = sB[0]; g.Cb[2] = utb;
    gemm_b<<<dim3(128, 2, 3), 256, 0, stream>>>(g, HID, 1);
  }
  // MLP layer 2 (relu)
  {
    GemmB g = {};
    g.A[0] = mA; g.Bt[0] = pWt[1]; g.bias[0] = pB[1]; g.Cb[0] = mB;
    g.A[1] = gb; g.Bt[1] = sWt[1]; g.bias[1] = sB[1]; g.Cb[1] = mB1;
    g.A[2] = utb; g.Bt[2] = sWt[1]; g.bias[2] = sB[1]; g.Cb[2] = mB2;
    gemm_b<<<dim3(128, 2, 3), 256, 0, stream>>>(g, HID, 1);
  }
  // MLP layer 3 (no relu) -> f32
  {
    GemmB g = {};
    g.A[0] = mB; g.Bt[0] = pWt[2]; g.bias[0] = pB[2]; g.Cf[0] = mlp_out;
    g.A[1] = mB1; g.Bt[1] = sWt[2]; g.bias[1] = sB[2]; g.Cf[1] = xw2;
    g.A[2] = mB2; g.Bt[2] = sWt[2]; g.bias[2] = sB[2]; g.Cf[2] = xt1;
    gemm_b<<<dim3(128, 2, 3), 256, 0, stream>>>(g, HID, 0);
  }
  // l2norm: projected, h1p(+Pb), h2p(+Qb)
  {
    NormB nb2 = {};
    nb2.X[0] = mlp_out; nb2.outF[0] = projected;
    nb2.X[1] = xw2; nb2.outF[1] = h1p; nb2.outB[1] = Pb;
    nb2.X[2] = xt1; nb2.outF[2] = h2p; nb2.outB[2] = Qb;
    l2norm_b<<<dim3(NN / 4, 3), 256, 0, stream>>>(nb2);
  }

  flash_sem2<<<dim3(128, 128, 3), 256, 0, stream>>>(Pb, Qb, Ra, Rb, Cr, Cc);
  contrast_k<<<NN / 4, 256, 0, stream>>>(projected, v_norm, u_emd, nbr, neg, &sums[0]);
  sem_fin<<<NN / 4, 256, 0, stream>>>(h1p, h2p, Ra, Rb, Cr, Cc, &sums[1]);
  final_k<<<1, 1, 0, stream>>>(sums, (float*)d_out);
}

// Round 3
// 3420.046 us; speedup vs baseline: 1.2415x; 1.0350x over previous
//
#include <hip/hip_runtime.h>
#include <hip/hip_bf16.h>

#define NN   16384
#define IND  512
#define HID  256
#define SAMP 8
#define CAP  64          // max nonzeros per adjacency row (mean ~16.4, P(>64) ~ e^-33)

typedef __bf16 bf16;
typedef __bf16 bf16x4 __attribute__((ext_vector_type(4)));
typedef __bf16 bf16x8 __attribute__((ext_vector_type(8)));
typedef float  f32x4  __attribute__((ext_vector_type(4)));

#define LOG2E_2 2.8853900817779268f   // 2/tau * log2(e) = 2*log2(e)

// async global->LDS, 16B per lane; LDS dest = wave-uniform base + lane*16
#define GLOAD_LDS16(gptr, lptr) \
  __builtin_amdgcn_global_load_lds((const __attribute__((address_space(1))) void*)(gptr), \
                                   (__attribute__((address_space(3))) void*)(lptr), 16, 0, 0)

// ---------------------------------------------------------------- conversions
__global__ void cvt_x(const float* __restrict__ a, bf16* __restrict__ oa,
                      const float* __restrict__ b, bf16* __restrict__ ob) {
  const float* src = blockIdx.y ? b : a;
  bf16* dst = blockIdx.y ? ob : oa;
  int stride = gridDim.x * blockDim.x;
  for (int i = blockIdx.x * blockDim.x + threadIdx.x; i < (NN * IND) / 4; i += stride) {
    float4 v = ((const float4*)src)[i];
    bf16x4 o = {(bf16)v.x, (bf16)v.y, (bf16)v.z, (bf16)v.w};
    *(bf16x4*)(dst + (size_t)i * 4) = o;
  }
}

struct WtArgs {
  const float* src[10];
  bf16* dst[10];
  int K[10];
};

// W [K,256] f32 -> Wt [256,K] bf16 (transposed so GEMM reads K-contiguous rows)
__global__ void cvt_weights(WtArgs a) {
  int w = blockIdx.y;
  int K = a.K[w];
  int total = K * HID;
  const float* s = a.src[w];
  bf16* d = a.dst[w];
  for (int i = blockIdx.x * blockDim.x + threadIdx.x; i < total; i += gridDim.x * blockDim.x) {
    int k = i >> 8, n = i & 255;          // i = k*256 + n
    d[n * K + k] = (bf16)s[i];
  }
}

// ---------------------------------------------------------------- adjacency scan (batched)
__global__ void scan_adj(const float* __restrict__ adjA, const float* __restrict__ adjB,
                         int* __restrict__ colsA, int* __restrict__ cntA,
                         int* __restrict__ colsB, int* __restrict__ cntB) {
  const float* adj = blockIdx.y ? adjB : adjA;
  int* cols = blockIdx.y ? colsB : colsA;
  int* cnt = blockIdx.y ? cntB : cntA;
  int r = blockIdx.x;
  __shared__ int c;
  if (threadIdx.x == 0) c = 0;
  __syncthreads();
  const float4* row = (const float4*)(adj + (size_t)r * NN);
  int* rc = cols + (size_t)r * CAP;
  #pragma unroll 4
  for (int i = threadIdx.x; i < NN / 4; i += 256) {
    float4 v = row[i];
    if (v.x != 0.f || v.y != 0.f || v.z != 0.f || v.w != 0.f) {
      if (v.x != 0.f) { int p = atomicAdd(&c, 1); if (p < CAP) rc[p] = 4 * i; }
      if (v.y != 0.f) { int p = atomicAdd(&c, 1); if (p < CAP) rc[p] = 4 * i + 1; }
      if (v.z != 0.f) { int p = atomicAdd(&c, 1); if (p < CAP) rc[p] = 4 * i + 2; }
      if (v.w != 0.f) { int p = atomicAdd(&c, 1); if (p < CAP) rc[p] = 4 * i + 3; }
    }
  }
  __syncthreads();
  if (threadIdx.x == 0) cnt[r] = (c < CAP) ? c : CAP;
}

// ---------------------------------------------------------------- SpMM (batched, opt fused l2norm)
struct SpmmB {
  const int* cols[4]; const int* cnt[4]; const float* X[4]; const float* bias[4];
  float* outF[4];   // raw f32 (scalar stores; may be 4B-aligned only)
  bf16* outB[4];    // raw bf16
  float* outNF[4];  // l2-normalized f32 (16B-aligned)
};
__global__ void spmm_b(SpmmB s) {
  int j = blockIdx.y;
  int wid = threadIdx.x >> 6, lane = threadIdx.x & 63;
  int r = blockIdx.x * 4 + wid;
  int c = s.cnt[j][r];
  float val = 1.0f / (float)(c > 0 ? c : 1);
  const int* rc = s.cols[j] + (size_t)r * CAP;
  const float* X = s.X[j];
  float ax = 0.f, ay = 0.f, az = 0.f, aw = 0.f;
  for (int t = 0; t < c; ++t) {
    int col = rc[t];
    float4 v = ((const float4*)(X + (size_t)col * HID))[lane];
    ax += v.x; ay += v.y; az += v.z; aw += v.w;
  }
  float4 b4 = ((const float4*)s.bias[j])[lane];
  ax = ax * val + b4.x; ay = ay * val + b4.y; az = az * val + b4.z; aw = aw * val + b4.w;
  if (s.outF[j]) {
    float* o = s.outF[j] + (size_t)r * HID + lane * 4;
    o[0] = ax; o[1] = ay; o[2] = az; o[3] = aw;
  }
  if (s.outB[j]) {
    bf16x4 ob = {(bf16)ax, (bf16)ay, (bf16)az, (bf16)aw};
    *(bf16x4*)(s.outB[j] + (size_t)r * HID + lane * 4) = ob;
  }
  if (s.outNF[j]) {
    float ss = ax * ax + ay * ay + az * az + aw * aw;
    #pragma unroll
    for (int off = 1; off < 64; off <<= 1) ss += __shfl_xor(ss, off);
    float inv = 1.0f / fmaxf(sqrtf(ss), 1e-12f);
    float4 o = {ax * inv, ay * inv, az * inv, aw * inv};
    ((float4*)(s.outNF[j] + (size_t)r * HID))[lane] = o;
  }
}

// ---------------------------------------------------------------- bf16 GEMM (batched, async staging)
// C[M=16384, N=256] = A[M,K] @ Bt[256,K]^T (+bias) (opt relu) -> f32 and/or bf16
// LDS XOR swizzle: LDS[row][chunk] = G[row][chunk ^ (row&7)]  (chunk = 16B unit)
struct GemmB {
  const bf16* A[3]; const bf16* Bt[3]; const float* bias[3];
  float* Cf[3]; bf16* Cb[3];
};
__global__ __launch_bounds__(256) void gemm_b(GemmB g, int K, int relu) {
  __shared__ bf16 As[128][64];
  __shared__ bf16 Bs[128][64];
  int j = blockIdx.z;
  const bf16* A = g.A[j];
  const bf16* Bt = g.Bt[j];
  int m0 = blockIdx.x * 128, n0 = blockIdx.y * 128;
  int tid = threadIdx.x, wid = tid >> 6, lane = tid & 63;
  int wm = wid >> 1, wn = wid & 1, q = lane >> 4, li = lane & 15;
  int r8 = lane >> 3, cc8 = lane & 7;    // 8 rows x 8 chunks per wave-instruction
  int csw = cc8 ^ r8;                    // swizzled source chunk for this lane
  f32x4 acc[4][4] = {};
  for (int k0 = 0; k0 < K; k0 += 64) {
    if (k0) __syncthreads();
    const bf16* gA = A + (size_t)(m0 + wid * 32 + r8) * K + k0 + csw * 8;
    const bf16* gB = Bt + (size_t)(n0 + wid * 32 + r8) * K + k0 + csw * 8;
    #pragma unroll
    for (int jj = 0; jj < 4; ++jj) {
      GLOAD_LDS16(gA + (size_t)jj * 8 * K, &As[wid * 32 + jj * 8][0]);
      GLOAD_LDS16(gB + (size_t)jj * 8 * K, &Bs[wid * 32 + jj * 8][0]);
    }
    __syncthreads();
    #pragma unroll
    for (int kk = 0; kk < 64; kk += 32) {
      int ca = (((q + (kk >> 3)) ^ (li & 7)) << 3);   // un-swizzle (row&7 == li&7)
      bf16x8 af[4], bfr[4];
      #pragma unroll
      for (int im = 0; im < 4; ++im) af[im] = *(const bf16x8*)(&As[wm * 64 + im * 16 + li][ca]);
      #pragma unroll
      for (int in = 0; in < 4; ++in) bfr[in] = *(const bf16x8*)(&Bs[wn * 64 + in * 16 + li][ca]);
      #pragma unroll
      for (int im = 0; im < 4; ++im)
        #pragma unroll
        for (int in = 0; in < 4; ++in)
          acc[im][in] = __builtin_amdgcn_mfma_f32_16x16x32_bf16(af[im], bfr[in], acc[im][in], 0, 0, 0);
    }
  }
  float* Cf = g.Cf[j];
  bf16* Cb = g.Cb[j];
  const float* bias = g.bias[j];
  #pragma unroll
  for (int im = 0; im < 4; ++im) {
    int grow0 = m0 + wm * 64 + im * 16 + q * 4;
    #pragma unroll
    for (int in = 0; in < 4; ++in) {
      int gcol = n0 + wn * 64 + in * 16 + li;
      float bv = bias ? bias[gcol] : 0.f;
      #pragma unroll
      for (int reg = 0; reg < 4; ++reg) {
        float v = acc[im][in][reg] + bv;
        if (relu) v = fmaxf(v, 0.f);
        size_t idx = (size_t)(grow0 + reg) * HID + gcol;
        if (Cf) Cf[idx] = v;
        if (Cb) Cb[idx] = (bf16)v;
      }
    }
  }
}

// ---------------------------------------------------------------- flash semi-loss v2 (swizzled)
// z=0: exp(2 P·P^T) rowsums -> Ra (upper triangle only; off-diag tiles add colsum to Ra too)
// z=1: same for Q -> Rb ; z=2: P·Q^T full, rowsum->Cr colsum->Cc
__global__ __launch_bounds__(256) void flash_sem2(
    const bf16* __restrict__ P, const bf16* __restrict__ Q,
    float* __restrict__ Ra, float* __restrict__ Rb,
    float* __restrict__ Cr, float* __restrict__ Cc) {
  __shared__ bf16 As[128][64];
  __shared__ bf16 Bs[128][64];
  int z = blockIdx.z;
  // 16x16 tile-group swizzle for L2 locality
  int bid = blockIdx.y * 128 + blockIdx.x;
  int grp = bid >> 8, loc = bid & 255;
  int bx = (grp & 7) * 16 + (loc & 15);
  int by = (grp >> 3) * 16 + (loc >> 4);
  if (z < 2 && by < bx) return;     // symmetric: upper triangle only
  const bf16* X = (z == 1) ? Q : P;
  const bf16* Y = (z == 0) ? P : Q;
  float* rowacc = (z == 0) ? Ra : (z == 1) ? Rb : Cr;
  float* colacc = (z == 2) ? Cc : rowacc;   // symmetric off-diag: colsum -> same acc
  bool docol = (z == 2) || (bx != by);
  int m0 = bx * 128, n0 = by * 128;
  int tid = threadIdx.x, wid = tid >> 6, lane = tid & 63;
  int wm = wid >> 1, wn = wid & 1, q = lane >> 4, li = lane & 15;
  int r8 = lane >> 3, cc8 = lane & 7;
  int csw = cc8 ^ r8;
  f32x4 acc[4][4] = {};
  for (int k0 = 0; k0 < HID; k0 += 64) {
    if (k0) __syncthreads();
    const bf16* gA = X + (size_t)(m0 + wid * 32 + r8) * HID + k0 + csw * 8;
    const bf16* gB = Y + (size_t)(n0 + wid * 32 + r8) * HID + k0 + csw * 8;
    #pragma unroll
    for (int jj = 0; jj < 4; ++jj) {
      GLOAD_LDS16(gA + (size_t)jj * 8 * HID, &As[wid * 32 + jj * 8][0]);
      GLOAD_LDS16(gB + (size_t)jj * 8 * HID, &Bs[wid * 32 + jj * 8][0]);
    }
    __syncthreads();
    #pragma unroll
    for (int kk = 0; kk < 64; kk += 32) {
      int ca = (((q + (kk >> 3)) ^ (li & 7)) << 3);
      bf16x8 af[4], bfr[4];
      #pragma unroll
      for (int im = 0; im < 4; ++im) af[im] = *(const bf16x8*)(&As[wm * 64 + im * 16 + li][ca]);
      #pragma unroll
      for (int in = 0; in < 4; ++in) bfr[in] = *(const bf16x8*)(&Bs[wn * 64 + in * 16 + li][ca]);
      #pragma unroll
      for (int im = 0; im < 4; ++im)
        #pragma unroll
        for (int in = 0; in < 4; ++in)
          acc[im][in] = __builtin_amdgcn_mfma_f32_16x16x32_bf16(af[im], bfr[in], acc[im][in], 0, 0, 0);
    }
  }
  float cs[4] = {0.f, 0.f, 0.f, 0.f};
  #pragma unroll
  for (int im = 0; im < 4; ++im) {
    #pragma unroll
    for (int reg = 0; reg < 4; ++reg) {
      float rs = 0.f;
      #pragma unroll
      for (int in = 0; in < 4; ++in) {
        float e = exp2f(acc[im][in][reg] * LOG2E_2);
        rs += e;
        cs[in] += e;
      }
      rs += __shfl_xor(rs, 1); rs += __shfl_xor(rs, 2);
      rs += __shfl_xor(rs, 4); rs += __shfl_xor(rs, 8);
      if (li == 0) atomicAdd(&rowacc[m0 + wm * 64 + im * 16 + q * 4 + reg], rs);
    }
  }
  if (docol) {
    #pragma unroll
    for (int in = 0; in < 4; ++in) {
      float v = cs[in];
      v += __shfl_xor(v, 16); v += __shfl_xor(v, 32);
      if (q == 0) atomicAdd(&colacc[n0 + wn * 64 + in * 16 + li], v);
    }
  }
}

// ---------------------------------------------------------------- l2norm (batched, one wave/row)
struct NormB { const float* X[3]; float* outF[3]; bf16* outB[3]; };
__global__ void l2norm_b(NormB n) {
  int j = blockIdx.y;
  int wid = threadIdx.x >> 6, lane = threadIdx.x & 63;
  int r = blockIdx.x * 4 + wid;
  float4 a = ((const float4*)(n.X[j] + (size_t)r * HID))[lane];
  float s = a.x * a.x + a.y * a.y + a.z * a.z + a.w * a.w;
  #pragma unroll
  for (int off = 1; off < 64; off <<= 1) s += __shfl_xor(s, off);
  float inv = 1.0f / fmaxf(sqrtf(s), 1e-12f);
  a.x *= inv; a.y *= inv; a.z *= inv; a.w *= inv;
  if (n.outF[j]) ((float4*)(n.outF[j] + (size_t)r * HID))[lane] = a;
  if (n.outB[j]) {
    bf16x4 b = {(bf16)a.x, (bf16)a.y, (bf16)a.z, (bf16)a.w};
    *(bf16x4*)(n.outB[j] + (size_t)r * HID + lane * 4) = b;
  }
}

// ---------------------------------------------------------------- contrastive (one wave/node)
__global__ void contrast_k(const float* __restrict__ proj, const float* __restrict__ vn,
                           const float* __restrict__ ue, const int* __restrict__ nbr,
                           const int* __restrict__ neg, float* __restrict__ gsum) {
  int wid = threadIdx.x >> 6, lane = threadIdx.x & 63;
  int n = blockIdx.x * 4 + wid;
  float4 p = ((const float4*)(proj + (size_t)n * HID))[lane];
  float4 v = ((const float4*)(vn + (size_t)n * HID))[lane];
  float du[SAMP], dn[SAMP];
  for (int s = 0; s < SAMP; ++s) {
    int iu = nbr[n * SAMP + s];
    float4 u = ((const float4*)(ue + (size_t)iu * HID))[lane];
    float d = p.x * u.x + p.y * u.y + p.z * u.z + p.w * u.w;
    #pragma unroll
    for (int off = 1; off < 64; off <<= 1) d += __shfl_xor(d, off);
    du[s] = d;
    int iv = neg[n * SAMP + s];
    float4 w = ((const float4*)(vn + (size_t)iv * HID))[lane];
    float d2 = v.x * w.x + v.y * w.y + v.z * w.z + v.w * w.w;
    #pragma unroll
    for (int off = 1; off < 64; off <<= 1) d2 += __shfl_xor(d2, off);
    dn[s] = d2;
  }
  float negsum = 0.f;
  for (int s = 0; s < SAMP; ++s) negsum += expf(2.f * dn[s]);
  float ns = 0.f, ps = 0.f;
  for (int s = 0; s < SAMP; ++s) {
    float pl = 2.f * du[s];
    ns += logf(expf(pl) + negsum);
    ps += pl;
  }
  if (lane == 0) atomicAdd(gsum, ns - ps);   // LAMBDA = 1
}

// ---------------------------------------------------------------- sem finalize (one wave/row)
__global__ void sem_fin(const float* __restrict__ P, const float* __restrict__ Q2,
                        const float* __restrict__ Ra, const float* __restrict__ Rb,
                        const float* __restrict__ Cr, const float* __restrict__ Cc,
                        float* __restrict__ ssum) {
  int wid = threadIdx.x >> 6, lane = threadIdx.x & 63;
  int i = blockIdx.x * 4 + wid;
  float4 a = ((const float4*)(P + (size_t)i * HID))[lane];
  float4 b = ((const float4*)(Q2 + (size_t)i * HID))[lane];
  float d = a.x * b.x + a.y * b.y + a.z * b.z + a.w * b.w;
  #pragma unroll
  for (int off = 1; off < 64; off <<= 1) d += __shfl_xor(d, off);
  float db = expf(2.f * d);
  float e2 = expf(2.f);      // diag(refl) of unit-norm rows
  float l1 = -logf(db / (Ra[i] + Cr[i] - e2));
  float l2 = -logf(db / (Rb[i] + Cc[i] - e2));
  if (lane == 0) atomicAdd(ssum, 0.5f * (l1 + l2));
}

__global__ void final_k(const float* __restrict__ sums, float* __restrict__ out) {
  float gacl = sums[0] / (float)(NN * SAMP);
  float sem = sums[1] / (float)NN;
  out[0] = gacl + 0.6f * sem;
  out[1] = gacl;
  out[2] = sem;
}

// ---------------------------------------------------------------- launch
extern "C" void kernel_launch(void* const* d_in, const int* in_sizes, int n_in,
                              void* d_out, int out_size, void* d_ws, size_t ws_size,
                              hipStream_t stream) {
  (void)in_sizes; (void)n_in; (void)out_size; (void)ws_size;
  const float* adj1 = (const float*)d_in[0];
  const float* adj2 = (const float*)d_in[1];
  const float* x1 = (const float*)d_in[2];
  const float* x2 = (const float*)d_in[3];
  const int* nbr = (const int*)d_in[4];
  const int* neg = (const int*)d_in[5];
  const float* W1 = (const float*)d_in[6];
  const float* b1 = (const float*)d_in[7];
  const float* W2 = (const float*)d_in[8];
  const float* b2 = (const float*)d_in[9];
  const float* tW1 = (const float*)d_in[10];
  const float* tb1 = (const float*)d_in[11];
  const float* tW2 = (const float*)d_in[12];
  const float* tb2 = (const float*)d_in[13];
  const float* pB[3] = {(const float*)d_in[15], (const float*)d_in[17], (const float*)d_in[19]};
  const float* sB[3] = {(const float*)d_in[21], (const float*)d_in[23], (const float*)d_in[25]};

  char* w = (char*)d_ws;
  auto alloc = [&](size_t bytes) -> char* {
    char* p = w;
    w += (bytes + 255) & ~(size_t)255;
    return p;
  };
  // accumulators first (one memset covers them)
  float* Ra = (float*)alloc((size_t)NN * 4);
  float* Rb = (float*)alloc((size_t)NN * 4);
  float* Cr = (float*)alloc((size_t)NN * 4);
  float* Cc = (float*)alloc((size_t)NN * 4);
  float* sums = (float*)alloc(256);             // [0]=gacl_sum, [1]=sem_sum
  size_t accBytes = (size_t)(w - (char*)d_ws);

  int* c1cols = (int*)alloc((size_t)NN * CAP * 4);
  int* c1cnt = (int*)alloc((size_t)NN * 4);
  int* c2cols = (int*)alloc((size_t)NN * CAP * 4);
  int* c2cnt = (int*)alloc((size_t)NN * 4);
  bf16* x1b = (bf16*)alloc((size_t)NN * IND * 2);
  bf16* x2b = (bf16*)alloc((size_t)NN * IND * 2);
  bf16* W1t = (bf16*)alloc((size_t)IND * HID * 2);
  bf16* tW1t = (bf16*)alloc((size_t)IND * HID * 2);
  bf16* W2t = (bf16*)alloc((size_t)HID * HID * 2);
  bf16* tW2t = (bf16*)alloc((size_t)HID * HID * 2);
  bf16* pWt[3], *sWt[3];
  for (int i = 0; i < 3; ++i) pWt[i] = (bf16*)alloc((size_t)HID * HID * 2);
  for (int i = 0; i < 3; ++i) sWt[i] = (bf16*)alloc((size_t)HID * HID * 2);
  const size_t FB = (size_t)NN * HID * 4;       // 16 MiB f32 buffers
  float* xw1 = (float*)alloc(FB);
  float* xw2 = (float*)alloc(FB);
  float* xt1 = (float*)alloc(FB);
  float* mlp_out = (float*)alloc(FB);
  float* projected = (float*)alloc(FB);
  float* h1p = (float*)alloc(FB);
  float* h2p = (float*)alloc(FB);
  float* v_norm = (float*)alloc(FB);
  float* gw = xw2;       // reuse: xw2 dead after spmm(h2)
  float* utw = xt1;      // reuse: xt1 dead after spmm(ut)
  float* u_emd = xw1;    // reuse: xw1 dead after spmm(g)
  const size_t BB = (size_t)NN * HID * 2;       // 8 MiB bf16 buffers
  bf16* h1b = (bf16*)alloc(BB);
  bf16* h2b = (bf16*)alloc(BB);
  bf16* gb = (bf16*)alloc(BB);
  bf16* h3b = (bf16*)alloc(BB);
  bf16* utb = (bf16*)alloc(BB);
  bf16* mA = (bf16*)alloc(BB);
  bf16* mB = (bf16*)alloc(BB);
  // overlays (regions dead by the time they're reused):
  bf16* mB1 = x1b;                       // x1b dead after layer-1 GEMMs
  bf16* mB2 = x1b + (size_t)NN * HID;    // second half of x1b
  bf16* Pb = gb;                         // gb dead after MLP layer 2
  bf16* Qb = utb;

  hipMemsetAsync(d_ws, 0, accBytes, stream);

  WtArgs wa;
  const float* wsrc[10] = {W1, tW1, W2, tW2,
                           (const float*)d_in[14], (const float*)d_in[16], (const float*)d_in[18],
                           (const float*)d_in[20], (const float*)d_in[22], (const float*)d_in[24]};
  bf16* wdst[10] = {W1t, tW1t, W2t, tW2t, pWt[0], pWt[1], pWt[2], sWt[0], sWt[1], sWt[2]};
  int wk[10] = {IND, IND, HID, HID, HID, HID, HID, HID, HID, HID};
  for (int i = 0; i < 10; ++i) { wa.src[i] = wsrc[i]; wa.dst[i] = wdst[i]; wa.K[i] = wk[i]; }
  cvt_weights<<<dim3(512, 10), 256, 0, stream>>>(wa);
  cvt_x<<<dim3(2048, 2), 256, 0, stream>>>(x1, x1b, x2, x2b);
  scan_adj<<<dim3(NN, 2), 256, 0, stream>>>(adj1, adj2, c1cols, c1cnt, c2cols, c2cnt);

  // xw1 = x1@W1, xw2 = x2@W1, xt1 = x1@tW1  (K=512, batched)
  {
    GemmB g = {};
    g.A[0] = x1b; g.Bt[0] = W1t; g.Cf[0] = xw1;
    g.A[1] = x2b; g.Bt[1] = W1t; g.Cf[1] = xw2;
    g.A[2] = x1b; g.Bt[2] = tW1t; g.Cf[2] = xt1;
    gemm_b<<<dim3(128, 2, 3), 256, 0, stream>>>(g, IND, 0);
  }
  // h1 = A1@xw1+b1, h2 = A1@xw2+b1, g = A2@xw1+b1, ut = A2@xt1+tb1
  {
    SpmmB s = {};
    s.cols[0] = c1cols; s.cnt[0] = c1cnt; s.X[0] = xw1; s.bias[0] = b1; s.outB[0] = h1b;
    s.cols[1] = c1cols; s.cnt[1] = c1cnt; s.X[1] = xw2; s.bias[1] = b1; s.outB[1] = h2b;
    s.cols[2] = c2cols; s.cnt[2] = c2cnt; s.X[2] = xw1; s.bias[2] = b1; s.outB[2] = gb;
    s.cols[3] = c2cols; s.cnt[3] = c2cnt; s.X[3] = xt1; s.bias[3] = tb1; s.outB[3] = utb;
    spmm_b<<<dim3(NN / 4, 4), 256, 0, stream>>>(s);
  }
  // gw = g@W2, utw = ut@tW2 (K=256, batched)
  {
    GemmB g = {};
    g.A[0] = gb; g.Bt[0] = W2t; g.Cf[0] = gw;
    g.A[1] = utb; g.Bt[1] = tW2t; g.Cf[1] = utw;
    gemm_b<<<dim3(128, 2, 2), 256, 0, stream>>>(g, HID, 0);
  }
  // h3 = A2@gw+b2 (-> d_out+3, h3b, v_norm) ; u_emd = l2norm(A2@utw+tb2)
  float* h3out = ((float*)d_out) + 3;
  {
    SpmmB s = {};
    s.cols[0] = c2cols; s.cnt[0] = c2cnt; s.X[0] = gw; s.bias[0] = b2;
    s.outF[0] = h3out; s.outB[0] = h3b; s.outNF[0] = v_norm;
    s.cols[1] = c2cols; s.cnt[1] = c2cnt; s.X[1] = utw; s.bias[1] = tb2;
    s.outNF[1] = u_emd;
    spmm_b<<<dim3(NN / 4, 2), 256, 0, stream>>>(s);
  }
  // MLP layer 1 (relu): proj(h3b), sem(h1b), sem(h2b)
  {
    GemmB g = {};
    g.A[0] = h3b; g.Bt[0] = pWt[0]; g.bias[0] = pB[0]; g.Cb[0] = mA;
    g.A[1] = h1b; g.Bt[1] = sWt[0]; g.bias[1] = sB[0]; g.Cb[1] = gb;
    g.A[2] = h2b; g.Bt[2] = sWt[0]; g.bias[2] = sB[0]; g.Cb[2] = utb;
    gemm_b<<<dim3(128, 2, 3), 256, 0, stream>>>(g, HID, 1);
  }
  // MLP layer 2 (relu)
  {
    GemmB g = {};
    g.A[0] = mA; g.Bt[0] = pWt[1]; g.bias[0] = pB[1]; g.Cb[0] = mB;
    g.A[1] = gb; g.Bt[1] = sWt[1]; g.bias[1] = sB[1]; g.Cb[1] = mB1;
    g.A[2] = utb; g.Bt[2] = sWt[1]; g.bias[2] = sB[1]; g.Cb[2] = mB2;
    gemm_b<<<dim3(128, 2, 3), 256, 0, stream>>>(g, HID, 1);
  }
  // MLP layer 3 (no relu) -> f32
  {
    GemmB g = {};
    g.A[0] = mB; g.Bt[0] = pWt[2]; g.bias[0] = pB[2]; g.Cf[0] = mlp_out;
    g.A[1] = mB1; g.Bt[1] = sWt[2]; g.bias[1] = sB[2]; g.Cf[1] = xw2;
    g.A[2] = mB2; g.Bt[2] = sWt[2]; g.bias[2] = sB[2]; g.Cf[2] = xt1;
    gemm_b<<<dim3(128, 2, 3), 256, 0, stream>>>(g, HID, 0);
  }
  // l2norm: projected, h1p(+Pb), h2p(+Qb)
  {
    NormB nb2 = {};
    nb2.X[0] = mlp_out; nb2.outF[0] = projected;
    nb2.X[1] = xw2; nb2.outF[1] = h1p; nb2.outB[1] = Pb;
    nb2.X[2] = xt1; nb2.outF[2] = h2p; nb2.outB[2] = Qb;
    l2norm_b<<<dim3(NN / 4, 3), 256, 0, stream>>>(nb2);
  }

  flash_sem2<<<dim3(128, 128, 3), 256, 0, stream>>>(Pb, Qb, Ra, Rb, Cr, Cc);
  contrast_k<<<NN / 4, 256, 0, stream>>>(projected, v_norm, u_emd, nbr, neg, &sums[0]);
  sem_fin<<<NN / 4, 256, 0, stream>>>(h1p, h2p, Ra, Rb, Cr, Cc, &sums[1]);
  final_k<<<1, 1, 0, stream>>>(sums, (float*)d_out);
}